// Round 1
// baseline (887.756 us; speedup 1.0000x reference)
//
#include <hip/hip_runtime.h>

// DinkNet: 2x GraphConv(512->128) encoders (clean + row-permuted) + PReLU,
// folded MLP (rowsum trick) -> logit[2N].
//
// Key identities:
//   (x[perm]) @ W = (x @ W)[perm]            -> one GEMM
//   (z @ mlpW + mlpb).sum(1) = z . rowsum(mlpW) + sum(mlpb)

// ---------------- graph prep ----------------

__global__ __launch_bounds__(256) void k_degrees(const int* __restrict__ src,
                                                 const int* __restrict__ dst,
                                                 int* __restrict__ deg_s,
                                                 int* __restrict__ deg_d, int E) {
  int e = blockIdx.x * 256 + threadIdx.x;
  if (e < E) {
    atomicAdd(&deg_s[src[e]], 1);
    atomicAdd(&deg_d[dst[e]], 1);
  }
}

__global__ __launch_bounds__(256) void k_norms(const int* __restrict__ deg_s,
                                               const int* __restrict__ deg_d,
                                               float* __restrict__ norm_o,
                                               float* __restrict__ norm_i, int N) {
  int i = blockIdx.x * 256 + threadIdx.x;
  if (i < N) {
    int a = deg_s[i]; if (a < 1) a = 1;
    int b = deg_d[i]; if (b < 1) b = 1;
    norm_o[i] = rsqrtf((float)a);
    norm_i[i] = rsqrtf((float)b);
  }
}

// exclusive scan of deg_d -> row_start, 3 kernels (chunk = 256)
__global__ __launch_bounds__(256) void k_scan_partial(const int* __restrict__ deg_d,
                                                      int* __restrict__ partials, int N) {
  __shared__ int sm[256];
  int t = threadIdx.x;
  int i = blockIdx.x * 256 + t;
  sm[t] = (i < N) ? deg_d[i] : 0;
  __syncthreads();
  for (int off = 128; off > 0; off >>= 1) {
    if (t < off) sm[t] += sm[t + off];
    __syncthreads();
  }
  if (t == 0) partials[blockIdx.x] = sm[0];
}

__global__ __launch_bounds__(512) void k_scan_top(const int* __restrict__ partials,
                                                  int* __restrict__ poff, int nb) {
  __shared__ int sm[512];
  int t = threadIdx.x;
  int v = (t < nb) ? partials[t] : 0;
  sm[t] = v;
  __syncthreads();
  for (int off = 1; off < 512; off <<= 1) {
    int add = (t >= off) ? sm[t - off] : 0;
    __syncthreads();
    sm[t] += add;
    __syncthreads();
  }
  if (t < nb) poff[t] = sm[t] - v;  // exclusive block offset
}

__global__ __launch_bounds__(256) void k_scan_final(const int* __restrict__ deg_d,
                                                    const int* __restrict__ poff,
                                                    int* __restrict__ row_start, int N) {
  __shared__ int sm[256];
  int t = threadIdx.x;
  int i = blockIdx.x * 256 + t;
  int v = (i < N) ? deg_d[i] : 0;
  sm[t] = v;
  __syncthreads();
  for (int off = 1; off < 256; off <<= 1) {
    int add = (t >= off) ? sm[t - off] : 0;
    __syncthreads();
    sm[t] += add;
    __syncthreads();
  }
  if (i < N) row_start[i] = poff[blockIdx.x] + sm[t] - v;  // exclusive
}

__global__ __launch_bounds__(256) void k_csr_fill(const int* __restrict__ src,
                                                  const int* __restrict__ dst,
                                                  const int* __restrict__ perm,
                                                  const float* __restrict__ norm_o,
                                                  const int* __restrict__ row_start,
                                                  int* __restrict__ cnt,
                                                  int* __restrict__ csr_s,
                                                  int* __restrict__ csr_ps,
                                                  float* __restrict__ csr_w, int E) {
  int e = blockIdx.x * 256 + threadIdx.x;
  if (e >= E) return;
  int s = src[e];
  int d = dst[e];
  int pos = row_start[d] + atomicAdd(&cnt[d], 1);
  csr_s[pos] = s;
  csr_ps[pos] = perm[s];
  csr_w[pos] = norm_o[s];
}

// ---------------- GEMM: h[N,128] = x[N,512] @ W[512,128], f32 ----------------
// BM=64, BN=128, BK=32; 256 threads; thread (tx=tid%16, ty=tid/16)
// thread computes rows ty*4..+3, cols {tx*4..+3} and {64+tx*4..+3}

__global__ __launch_bounds__(256) void k_gemm(const float* __restrict__ X,
                                              const float* __restrict__ W,
                                              float* __restrict__ H, int M) {
  __shared__ float As[32][65];   // [k][m], +1 pad -> <=2-way on writes
  __shared__ float Bs[32][128];  // [k][n]

  const int tid = threadIdx.x;
  const int tx = tid & 15;
  const int ty = tid >> 4;
  const int block_row = blockIdx.x * 64;

  float acc[4][8];
#pragma unroll
  for (int i = 0; i < 4; i++)
#pragma unroll
    for (int j = 0; j < 8; j++) acc[i][j] = 0.f;

  for (int k0 = 0; k0 < 512; k0 += 32) {
    // stage A tile: 64 rows x 32 k = 512 float4; 2 per thread
#pragma unroll
    for (int it = 0; it < 2; it++) {
      int idx = tid + it * 256;
      int row = idx >> 3;
      int kc = (idx & 7) * 4;
      int gr = block_row + row;
      float4 v = make_float4(0.f, 0.f, 0.f, 0.f);
      if (gr < M) v = *(const float4*)(X + (size_t)gr * 512 + k0 + kc);
      As[kc + 0][row] = v.x;
      As[kc + 1][row] = v.y;
      As[kc + 2][row] = v.z;
      As[kc + 3][row] = v.w;
    }
    // stage B tile: 32 k x 128 n = 1024 float4-elems/4 = 1024 float4? (4096 f) -> 4 float4/thread
#pragma unroll
    for (int it = 0; it < 4; it++) {
      int idx = tid + it * 256;
      int kr = idx >> 5;
      int nc = (idx & 31) * 4;
      *(float4*)&Bs[kr][nc] = *(const float4*)(W + (size_t)(k0 + kr) * 128 + nc);
    }
    __syncthreads();

#pragma unroll
    for (int k = 0; k < 32; k++) {
      float a[4], b[8];
#pragma unroll
      for (int i = 0; i < 4; i++) a[i] = As[k][ty * 4 + i];
#pragma unroll
      for (int j = 0; j < 4; j++) b[j] = Bs[k][tx * 4 + j];
#pragma unroll
      for (int j = 0; j < 4; j++) b[4 + j] = Bs[k][64 + tx * 4 + j];
#pragma unroll
      for (int i = 0; i < 4; i++)
#pragma unroll
        for (int j = 0; j < 8; j++) acc[i][j] += a[i] * b[j];
    }
    __syncthreads();
  }

#pragma unroll
  for (int i = 0; i < 4; i++) {
    int gr = block_row + ty * 4 + i;
    if (gr < M) {
      float4 v0 = make_float4(acc[i][0], acc[i][1], acc[i][2], acc[i][3]);
      float4 v1 = make_float4(acc[i][4], acc[i][5], acc[i][6], acc[i][7]);
      *(float4*)(H + (size_t)gr * 128 + tx * 4) = v0;
      *(float4*)(H + (size_t)gr * 128 + 64 + tx * 4) = v1;
    }
  }
}

// ---------------- folded MLP vector ----------------
__global__ __launch_bounds__(128) void k_wsum(const float* __restrict__ mlpW,
                                              const float* __restrict__ mlpb,
                                              float* __restrict__ wsum,
                                              float* __restrict__ bsum) {
  __shared__ float sb[128];
  int k = threadIdx.x;
  float s = 0.f;
  for (int j = 0; j < 128; j++) s += mlpW[k * 128 + j];
  wsum[k] = s;
  sb[k] = mlpb[k];
  __syncthreads();
  for (int off = 64; off > 0; off >>= 1) {
    if (k < off) sb[k] += sb[k + off];
    __syncthreads();
  }
  if (k == 0) bsum[0] = sb[0];
}

// ---------------- aggregation + fused epilogue ----------------
// one wave per dst node; lane l owns features 2l, 2l+1 (float2)
__global__ __launch_bounds__(256) void k_agg(const float* __restrict__ H,
                                             const int* __restrict__ row_start,
                                             const int* __restrict__ deg_d,
                                             const int* __restrict__ csr_s,
                                             const int* __restrict__ csr_ps,
                                             const float* __restrict__ csr_w,
                                             const float* __restrict__ norm_i,
                                             const float* __restrict__ bias,
                                             const float* __restrict__ alpha,
                                             const float* __restrict__ wsum,
                                             const float* __restrict__ bsum,
                                             float* __restrict__ out, int N) {
  int wave = (blockIdx.x * 256 + threadIdx.x) >> 6;
  int lane = threadIdx.x & 63;
  if (wave >= N) return;

  const float2* __restrict__ H2 = (const float2*)H;
  int start = row_start[wave];
  int cnt = deg_d[wave];

  float2 a1 = make_float2(0.f, 0.f);
  float2 a2 = make_float2(0.f, 0.f);
  for (int j = 0; j < cnt; j++) {
    int e = start + j;
    int s = csr_s[e];
    int ps = csr_ps[e];
    float w = csr_w[e];
    float2 v1 = H2[(size_t)s * 64 + lane];
    float2 v2 = H2[(size_t)ps * 64 + lane];
    a1.x = fmaf(v1.x, w, a1.x);
    a1.y = fmaf(v1.y, w, a1.y);
    a2.x = fmaf(v2.x, w, a2.x);
    a2.y = fmaf(v2.y, w, a2.y);
  }

  float ni = norm_i[wave];
  float2 bb = ((const float2*)bias)[lane];
  float2 al = ((const float2*)alpha)[lane];
  float2 ws = ((const float2*)wsum)[lane];
  float bs = bsum[0];

  float g1x = a1.x * ni + bb.x;
  float g1y = a1.y * ni + bb.y;
  float g2x = a2.x * ni + bb.x;
  float g2y = a2.y * ni + bb.y;
  // PReLU
  g1x = (g1x >= 0.f) ? g1x : al.x * g1x;
  g1y = (g1y >= 0.f) ? g1y : al.y * g1y;
  g2x = (g2x >= 0.f) ? g2x : al.x * g2x;
  g2y = (g2y >= 0.f) ? g2y : al.y * g2y;

  float p1 = g1x * ws.x + g1y * ws.y;
  float p2 = g2x * ws.x + g2y * ws.y;
  for (int off = 32; off > 0; off >>= 1) {
    p1 += __shfl_down(p1, off);
    p2 += __shfl_down(p2, off);
  }
  if (lane == 0) {
    out[wave] = p1 + bs;
    out[N + wave] = p2 + bs;
  }
}

// ---------------- launch ----------------

extern "C" void kernel_launch(void* const* d_in, const int* in_sizes, int n_in,
                              void* d_out, int out_size, void* d_ws, size_t ws_size,
                              hipStream_t stream) {
  const float* x = (const float*)d_in[0];
  const int* src = (const int*)d_in[1];
  const int* dst = (const int*)d_in[2];
  const int* perm = (const int*)d_in[3];
  const float* W = (const float*)d_in[4];
  const float* bias = (const float*)d_in[5];
  const float* alpha = (const float*)d_in[6];
  const float* mlpW = (const float*)d_in[7];
  const float* mlpb = (const float*)d_in[8];

  const int E = in_sizes[1];
  const int N = in_sizes[3];
  float* out = (float*)d_out;

  char* ws = (char*)d_ws;
  size_t off = 0;
  auto alloc = [&](size_t bytes) -> void* {
    void* p = ws + off;
    off = (off + bytes + 255) & ~(size_t)255;
    return p;
  };

  float* h = (float*)alloc((size_t)N * 128 * sizeof(float));
  int* deg_s = (int*)alloc((size_t)N * sizeof(int));
  int* deg_d = (int*)alloc((size_t)N * sizeof(int));
  int* cnt = (int*)alloc((size_t)N * sizeof(int));
  float* norm_o = (float*)alloc((size_t)N * sizeof(float));
  float* norm_i = (float*)alloc((size_t)N * sizeof(float));
  int* row_start = (int*)alloc((size_t)N * sizeof(int));
  int* csr_s = (int*)alloc((size_t)E * sizeof(int));
  int* csr_ps = (int*)alloc((size_t)E * sizeof(int));
  float* csr_w = (float*)alloc((size_t)E * sizeof(float));
  float* wsum = (float*)alloc(128 * sizeof(float));
  float* bsum = (float*)alloc(256);
  int* partials = (int*)alloc(512 * sizeof(int));
  int* poff = (int*)alloc(512 * sizeof(int));

  const int nbN = (N + 255) / 256;   // 391 (<=512 for scan_top)
  const int nbE = (E + 255) / 256;

  hipMemsetAsync(deg_s, 0, (size_t)N * sizeof(int), stream);
  hipMemsetAsync(deg_d, 0, (size_t)N * sizeof(int), stream);
  hipMemsetAsync(cnt, 0, (size_t)N * sizeof(int), stream);

  k_degrees<<<nbE, 256, 0, stream>>>(src, dst, deg_s, deg_d, E);
  k_norms<<<nbN, 256, 0, stream>>>(deg_s, deg_d, norm_o, norm_i, N);
  k_scan_partial<<<nbN, 256, 0, stream>>>(deg_d, partials, N);
  k_scan_top<<<1, 512, 0, stream>>>(partials, poff, nbN);
  k_scan_final<<<nbN, 256, 0, stream>>>(deg_d, poff, row_start, N);
  k_csr_fill<<<nbE, 256, 0, stream>>>(src, dst, perm, norm_o, row_start, cnt,
                                      csr_s, csr_ps, csr_w, E);

  k_gemm<<<(N + 63) / 64, 256, 0, stream>>>(x, W, h, N);
  k_wsum<<<1, 128, 0, stream>>>(mlpW, mlpb, wsum, bsum);

  k_agg<<<(N + 3) / 4, 256, 0, stream>>>(h, row_start, deg_d, csr_s, csr_ps, csr_w,
                                         norm_i, bias, alpha, wsum, bsum, out, N);
}

// Round 2
// 728.871 us; speedup vs baseline: 1.2180x; 1.2180x over previous
//
#include <hip/hip_runtime.h>

// DinkNet: 2x GraphConv(512->128) encoders (clean + row-permuted) + PReLU,
// folded MLP (rowsum trick) -> logit[2N].
//
// Identities:  (x[perm])@W = (x@W)[perm]  -> one GEMM
//              (z@mlpW+mlpb).sum(1) = z . rowsum(mlpW) + sum(mlpb)
// Round 2: h stored bf16 (halves gather bytes), bf16 MFMA GEMM,
//          CSR packed as int4/edge (1 cache line, not 3).

typedef __bf16 bf16x8 __attribute__((ext_vector_type(8)));
typedef float f32x4 __attribute__((ext_vector_type(4)));

__device__ inline unsigned short f2bf(float f) {
  unsigned u = __float_as_uint(f);
  u += 0x7fffu + ((u >> 16) & 1u);  // RNE
  return (unsigned short)(u >> 16);
}
__device__ inline float2 bfpair(unsigned u) {
  float2 r;
  r.x = __uint_as_float(u << 16);
  r.y = __uint_as_float(u & 0xffff0000u);
  return r;
}

// ---------------- graph prep ----------------

__global__ __launch_bounds__(256) void k_degrees(const int* __restrict__ src,
                                                 const int* __restrict__ dst,
                                                 int* __restrict__ deg_s,
                                                 int* __restrict__ deg_d, int E) {
  int e = blockIdx.x * 256 + threadIdx.x;
  if (e < E) {
    atomicAdd(&deg_s[src[e]], 1);
    atomicAdd(&deg_d[dst[e]], 1);
  }
}

__global__ __launch_bounds__(256) void k_norms(const int* __restrict__ deg_s,
                                               const int* __restrict__ deg_d,
                                               float* __restrict__ norm_o,
                                               float* __restrict__ norm_i, int N) {
  int i = blockIdx.x * 256 + threadIdx.x;
  if (i < N) {
    int a = deg_s[i]; if (a < 1) a = 1;
    int b = deg_d[i]; if (b < 1) b = 1;
    norm_o[i] = rsqrtf((float)a);
    norm_i[i] = rsqrtf((float)b);
  }
}

__global__ __launch_bounds__(256) void k_scan_partial(const int* __restrict__ deg_d,
                                                      int* __restrict__ partials, int N) {
  __shared__ int sm[256];
  int t = threadIdx.x;
  int i = blockIdx.x * 256 + t;
  sm[t] = (i < N) ? deg_d[i] : 0;
  __syncthreads();
  for (int off = 128; off > 0; off >>= 1) {
    if (t < off) sm[t] += sm[t + off];
    __syncthreads();
  }
  if (t == 0) partials[blockIdx.x] = sm[0];
}

__global__ __launch_bounds__(512) void k_scan_top(const int* __restrict__ partials,
                                                  int* __restrict__ poff, int nb) {
  __shared__ int sm[512];
  int t = threadIdx.x;
  int v = (t < nb) ? partials[t] : 0;
  sm[t] = v;
  __syncthreads();
  for (int off = 1; off < 512; off <<= 1) {
    int add = (t >= off) ? sm[t - off] : 0;
    __syncthreads();
    sm[t] += add;
    __syncthreads();
  }
  if (t < nb) poff[t] = sm[t] - v;
}

__global__ __launch_bounds__(256) void k_scan_final(const int* __restrict__ deg_d,
                                                    const int* __restrict__ poff,
                                                    int* __restrict__ row_start, int N) {
  __shared__ int sm[256];
  int t = threadIdx.x;
  int i = blockIdx.x * 256 + t;
  int v = (i < N) ? deg_d[i] : 0;
  sm[t] = v;
  __syncthreads();
  for (int off = 1; off < 256; off <<= 1) {
    int add = (t >= off) ? sm[t - off] : 0;
    __syncthreads();
    sm[t] += add;
    __syncthreads();
  }
  if (i < N) row_start[i] = poff[blockIdx.x] + sm[t] - v;
}

__global__ __launch_bounds__(256) void k_csr_fill(const int* __restrict__ src,
                                                  const int* __restrict__ dst,
                                                  const int* __restrict__ perm,
                                                  const float* __restrict__ norm_o,
                                                  const int* __restrict__ row_start,
                                                  int* __restrict__ cnt,
                                                  int4* __restrict__ csr, int E) {
  int e = blockIdx.x * 256 + threadIdx.x;
  if (e >= E) return;
  int s = src[e];
  int d = dst[e];
  int pos = row_start[d] + atomicAdd(&cnt[d], 1);
  csr[pos] = make_int4(s, perm[s], __float_as_int(norm_o[s]), 0);
}

// ---------------- W -> WT bf16 [128][512] ----------------
__global__ __launch_bounds__(256) void k_castw(const float* __restrict__ W,
                                               unsigned short* __restrict__ WT) {
  int i = blockIdx.x * 256 + threadIdx.x;  // i < 512*128
  int k = i >> 7;
  int n = i & 127;
  WT[n * 512 + k] = f2bf(W[i]);
}

// ---------------- GEMM: h[N,128](bf16) = x[N,512](f32) @ W ----------------
// BM=64, BN=128, BK=32; 256 threads = 4 waves; wave w owns rows 16w..16w+15.
// MFMA 16x16x32 bf16: A frag A[m=lane&15][k=quad*8+j]; B frag B[k][n=lane&15];
// C/D: col=lane&15, row=quad*4+reg.
#define AS_STRIDE 40
__global__ __launch_bounds__(256) void k_gemm(const float* __restrict__ X,
                                              const unsigned short* __restrict__ WT,
                                              unsigned short* __restrict__ H, int M) {
  __shared__ __align__(16) unsigned short smem[8192];  // A:0..2559, B:2560..7679; Out overlay 0..8191
  unsigned short* As = smem;                 // [64][AS_STRIDE]
  unsigned short* Bs = smem + 64 * AS_STRIDE;  // [128][AS_STRIDE] (k-contiguous, i.e. W^T)

  const int tid = threadIdx.x;
  const int wave = tid >> 6;
  const int lane = tid & 63;
  const int m = lane & 15;
  const int quad = lane >> 4;
  const int block_row = blockIdx.x * 64;

  f32x4 acc[8];
#pragma unroll
  for (int t = 0; t < 8; t++) acc[t] = (f32x4){0.f, 0.f, 0.f, 0.f};

  for (int k0 = 0; k0 < 512; k0 += 32) {
    // stage A: 64 rows x 32 k f32 -> bf16. 512 float4 loads, 2/thread.
#pragma unroll
    for (int it = 0; it < 2; it++) {
      int idx = tid + it * 256;
      int row = idx >> 3;
      int kc = (idx & 7) * 4;
      int gr = block_row + row;
      float4 v = make_float4(0.f, 0.f, 0.f, 0.f);
      if (gr < M) v = *(const float4*)(X + (size_t)gr * 512 + k0 + kc);
      ushort4 b;
      b.x = f2bf(v.x); b.y = f2bf(v.y); b.z = f2bf(v.z); b.w = f2bf(v.w);
      *(ushort4*)&As[row * AS_STRIDE + kc] = b;
    }
    // stage B: 128 n x 32 k bf16 from WT (k-contiguous). 2x 16B/thread.
#pragma unroll
    for (int it = 0; it < 2; it++) {
      int idx = tid + it * 256;
      int n = idx >> 2;
      int kc = (idx & 3) * 8;
      *(int4*)&Bs[n * AS_STRIDE + kc] = *(const int4*)(WT + (size_t)n * 512 + k0 + kc);
    }
    __syncthreads();

    bf16x8 a = *(bf16x8*)&As[(wave * 16 + m) * AS_STRIDE + quad * 8];
#pragma unroll
    for (int t = 0; t < 8; t++) {
      bf16x8 b = *(bf16x8*)&Bs[(t * 16 + m) * AS_STRIDE + quad * 8];
      acc[t] = __builtin_amdgcn_mfma_f32_16x16x32_bf16(a, b, acc[t], 0, 0, 0);
    }
    __syncthreads();
  }

  // epilogue: acc -> LDS (bf16, row-major 64x128) -> coalesced global stores
  // (smem reuse is safe: barrier above guarantees all waves done with As/Bs)
#pragma unroll
  for (int t = 0; t < 8; t++) {
    int col = t * 16 + m;
#pragma unroll
    for (int r = 0; r < 4; r++) {
      int row = wave * 16 + quad * 4 + r;
      smem[row * 128 + col] = f2bf(acc[t][r]);
    }
  }
  __syncthreads();
#pragma unroll
  for (int it = 0; it < 4; it++) {
    int idx = tid + it * 256;     // 1024 int4 total
    int row = idx >> 4;
    int c8 = (idx & 15) * 8;
    int gr = block_row + row;
    if (gr < M)
      *(int4*)(H + (size_t)gr * 128 + c8) = *(int4*)&smem[row * 128 + c8];
  }
}

// ---------------- folded MLP vector ----------------
__global__ __launch_bounds__(128) void k_wsum(const float* __restrict__ mlpW,
                                              const float* __restrict__ mlpb,
                                              float* __restrict__ wsum,
                                              float* __restrict__ bsum) {
  __shared__ float sb[128];
  int k = threadIdx.x;
  float s = 0.f;
  for (int j = 0; j < 128; j++) s += mlpW[k * 128 + j];
  wsum[k] = s;
  sb[k] = mlpb[k];
  __syncthreads();
  for (int off = 64; off > 0; off >>= 1) {
    if (k < off) sb[k] += sb[k + off];
    __syncthreads();
  }
  if (k == 0) bsum[0] = sb[0];
}

// ---------------- aggregation + fused epilogue ----------------
// one wave per dst node; lane l owns features 2l,2l+1 (one uint = 2 bf16)
__global__ __launch_bounds__(256) void k_agg(const unsigned short* __restrict__ H,
                                             const int* __restrict__ row_start,
                                             const int* __restrict__ deg_d,
                                             const int4* __restrict__ csr,
                                             const float* __restrict__ norm_i,
                                             const float* __restrict__ bias,
                                             const float* __restrict__ alpha,
                                             const float* __restrict__ wsum,
                                             const float* __restrict__ bsum,
                                             float* __restrict__ out, int N) {
  int wave = (blockIdx.x * 256 + threadIdx.x) >> 6;
  int lane = threadIdx.x & 63;
  if (wave >= N) return;

  const unsigned* __restrict__ H32 = (const unsigned*)H;  // 64 uints per row
  int start = row_start[wave];
  int cnt = deg_d[wave];

  float2 a1 = make_float2(0.f, 0.f);
  float2 a2 = make_float2(0.f, 0.f);
  for (int j = 0; j < cnt; j++) {
    int4 ed = csr[start + j];
    float w = __int_as_float(ed.z);
    float2 v1 = bfpair(H32[(size_t)ed.x * 64 + lane]);
    float2 v2 = bfpair(H32[(size_t)ed.y * 64 + lane]);
    a1.x = fmaf(v1.x, w, a1.x);
    a1.y = fmaf(v1.y, w, a1.y);
    a2.x = fmaf(v2.x, w, a2.x);
    a2.y = fmaf(v2.y, w, a2.y);
  }

  float ni = norm_i[wave];
  float2 bb = ((const float2*)bias)[lane];
  float2 al = ((const float2*)alpha)[lane];
  float2 ws = ((const float2*)wsum)[lane];
  float bs = bsum[0];

  float g1x = a1.x * ni + bb.x;
  float g1y = a1.y * ni + bb.y;
  float g2x = a2.x * ni + bb.x;
  float g2y = a2.y * ni + bb.y;
  g1x = (g1x >= 0.f) ? g1x : al.x * g1x;
  g1y = (g1y >= 0.f) ? g1y : al.y * g1y;
  g2x = (g2x >= 0.f) ? g2x : al.x * g2x;
  g2y = (g2y >= 0.f) ? g2y : al.y * g2y;

  float p1 = g1x * ws.x + g1y * ws.y;
  float p2 = g2x * ws.x + g2y * ws.y;
  for (int off = 32; off > 0; off >>= 1) {
    p1 += __shfl_down(p1, off);
    p2 += __shfl_down(p2, off);
  }
  if (lane == 0) {
    out[wave] = p1 + bs;
    out[N + wave] = p2 + bs;
  }
}

// ---------------- launch ----------------

extern "C" void kernel_launch(void* const* d_in, const int* in_sizes, int n_in,
                              void* d_out, int out_size, void* d_ws, size_t ws_size,
                              hipStream_t stream) {
  const float* x = (const float*)d_in[0];
  const int* src = (const int*)d_in[1];
  const int* dst = (const int*)d_in[2];
  const int* perm = (const int*)d_in[3];
  const float* W = (const float*)d_in[4];
  const float* bias = (const float*)d_in[5];
  const float* alpha = (const float*)d_in[6];
  const float* mlpW = (const float*)d_in[7];
  const float* mlpb = (const float*)d_in[8];

  const int E = in_sizes[1];
  const int N = in_sizes[3];
  float* out = (float*)d_out;

  char* ws = (char*)d_ws;
  size_t off = 0;
  auto alloc = [&](size_t bytes) -> void* {
    void* p = ws + off;
    off = (off + bytes + 255) & ~(size_t)255;
    return p;
  };

  unsigned short* h = (unsigned short*)alloc((size_t)N * 128 * sizeof(unsigned short));
  int4* csr = (int4*)alloc((size_t)E * sizeof(int4));
  unsigned short* WT = (unsigned short*)alloc(512 * 128 * sizeof(unsigned short));
  int* deg_s = (int*)alloc((size_t)N * sizeof(int));
  int* deg_d = (int*)alloc((size_t)N * sizeof(int));
  int* cnt = (int*)alloc((size_t)N * sizeof(int));
  float* norm_o = (float*)alloc((size_t)N * sizeof(float));
  float* norm_i = (float*)alloc((size_t)N * sizeof(float));
  int* row_start = (int*)alloc((size_t)N * sizeof(int));
  float* wsum = (float*)alloc(128 * sizeof(float));
  float* bsum = (float*)alloc(256);
  int* partials = (int*)alloc(512 * sizeof(int));
  int* poff = (int*)alloc(512 * sizeof(int));

  const int nbN = (N + 255) / 256;  // 391 (<=512 for scan_top)
  const int nbE = (E + 255) / 256;

  hipMemsetAsync(deg_s, 0, (size_t)N * sizeof(int), stream);
  hipMemsetAsync(deg_d, 0, (size_t)N * sizeof(int), stream);
  hipMemsetAsync(cnt, 0, (size_t)N * sizeof(int), stream);

  k_degrees<<<nbE, 256, 0, stream>>>(src, dst, deg_s, deg_d, E);
  k_norms<<<nbN, 256, 0, stream>>>(deg_s, deg_d, norm_o, norm_i, N);
  k_scan_partial<<<nbN, 256, 0, stream>>>(deg_d, partials, N);
  k_scan_top<<<1, 512, 0, stream>>>(partials, poff, nbN);
  k_scan_final<<<nbN, 256, 0, stream>>>(deg_d, poff, row_start, N);
  k_csr_fill<<<nbE, 256, 0, stream>>>(src, dst, perm, norm_o, row_start, cnt, csr, E);

  k_castw<<<512 * 128 / 256, 256, 0, stream>>>(W, WT);
  k_gemm<<<(N + 63) / 64, 256, 0, stream>>>(x, WT, h, N);
  k_wsum<<<1, 128, 0, stream>>>(mlpW, mlpb, wsum, bsum);

  k_agg<<<(N + 3) / 4, 256, 0, stream>>>(h, row_start, deg_d, csr, norm_i,
                                         bias, alpha, wsum, bsum, out, N);
}

// Round 3
// 663.404 us; speedup vs baseline: 1.3382x; 1.0987x over previous
//
#include <hip/hip_runtime.h>

// DinkNet: 2x GraphConv(512->128) encoders (clean + row-permuted) + PReLU,
// folded MLP (rowsum trick) -> logit[2N].
//
// Identities:  (x[perm])@W = (x@W)[perm]  -> one GEMM
//              (z@mlpW+mlpb).sum(1) = z . rowsum(mlpW) + sum(mlpb)
// Round 3: k_agg processes 4 edges/wave-iter (quad-split wave) -> 8
//          outstanding 256B gathers (latency-bound fix); {perm,norm_o}
//          packed to one int2 line for csr_fill.

typedef __bf16 bf16x8 __attribute__((ext_vector_type(8)));
typedef float f32x4 __attribute__((ext_vector_type(4)));

__device__ inline unsigned short f2bf(float f) {
  unsigned u = __float_as_uint(f);
  u += 0x7fffu + ((u >> 16) & 1u);  // RNE
  return (unsigned short)(u >> 16);
}
__device__ inline float2 bfpair(unsigned u) {
  float2 r;
  r.x = __uint_as_float(u << 16);
  r.y = __uint_as_float(u & 0xffff0000u);
  return r;
}

// ---------------- graph prep ----------------

__global__ __launch_bounds__(256) void k_degrees(const int* __restrict__ src,
                                                 const int* __restrict__ dst,
                                                 int* __restrict__ deg_s,
                                                 int* __restrict__ deg_d, int E) {
  int e = blockIdx.x * 256 + threadIdx.x;
  if (e < E) {
    atomicAdd(&deg_s[src[e]], 1);
    atomicAdd(&deg_d[dst[e]], 1);
  }
}

// pn[i] = {perm[i], bits(rsqrt(max(deg_s,1)))}; norm_i = rsqrt(max(deg_d,1))
__global__ __launch_bounds__(256) void k_norms(const int* __restrict__ deg_s,
                                               const int* __restrict__ deg_d,
                                               const int* __restrict__ perm,
                                               int2* __restrict__ pn,
                                               float* __restrict__ norm_i, int N) {
  int i = blockIdx.x * 256 + threadIdx.x;
  if (i < N) {
    int a = deg_s[i]; if (a < 1) a = 1;
    int b = deg_d[i]; if (b < 1) b = 1;
    pn[i] = make_int2(perm[i], __float_as_int(rsqrtf((float)a)));
    norm_i[i] = rsqrtf((float)b);
  }
}

__global__ __launch_bounds__(256) void k_scan_partial(const int* __restrict__ deg_d,
                                                      int* __restrict__ partials, int N) {
  __shared__ int sm[256];
  int t = threadIdx.x;
  int i = blockIdx.x * 256 + t;
  sm[t] = (i < N) ? deg_d[i] : 0;
  __syncthreads();
  for (int off = 128; off > 0; off >>= 1) {
    if (t < off) sm[t] += sm[t + off];
    __syncthreads();
  }
  if (t == 0) partials[blockIdx.x] = sm[0];
}

__global__ __launch_bounds__(512) void k_scan_top(const int* __restrict__ partials,
                                                  int* __restrict__ poff, int nb) {
  __shared__ int sm[512];
  int t = threadIdx.x;
  int v = (t < nb) ? partials[t] : 0;
  sm[t] = v;
  __syncthreads();
  for (int off = 1; off < 512; off <<= 1) {
    int add = (t >= off) ? sm[t - off] : 0;
    __syncthreads();
    sm[t] += add;
    __syncthreads();
  }
  if (t < nb) poff[t] = sm[t] - v;
}

__global__ __launch_bounds__(256) void k_scan_final(const int* __restrict__ deg_d,
                                                    const int* __restrict__ poff,
                                                    int* __restrict__ row_start, int N) {
  __shared__ int sm[256];
  int t = threadIdx.x;
  int i = blockIdx.x * 256 + t;
  int v = (i < N) ? deg_d[i] : 0;
  sm[t] = v;
  __syncthreads();
  for (int off = 1; off < 256; off <<= 1) {
    int add = (t >= off) ? sm[t - off] : 0;
    __syncthreads();
    sm[t] += add;
    __syncthreads();
  }
  if (i < N) row_start[i] = poff[blockIdx.x] + sm[t] - v;
}

__global__ __launch_bounds__(256) void k_csr_fill(const int* __restrict__ src,
                                                  const int* __restrict__ dst,
                                                  const int2* __restrict__ pn,
                                                  const int* __restrict__ row_start,
                                                  int* __restrict__ cnt,
                                                  int4* __restrict__ csr, int E) {
  int e = blockIdx.x * 256 + threadIdx.x;
  if (e >= E) return;
  int s = src[e];
  int d = dst[e];
  int2 p = pn[s];  // one line: {perm[s], norm_o[s]}
  int pos = row_start[d] + atomicAdd(&cnt[d], 1);
  csr[pos] = make_int4(s, p.x, p.y, 0);
}

// ---------------- W -> WT bf16 [128][512] ----------------
__global__ __launch_bounds__(256) void k_castw(const float* __restrict__ W,
                                               unsigned short* __restrict__ WT) {
  int i = blockIdx.x * 256 + threadIdx.x;  // i < 512*128
  int k = i >> 7;
  int n = i & 127;
  WT[n * 512 + k] = f2bf(W[i]);
}

// ---------------- GEMM: h[N,128](bf16) = x[N,512](f32) @ W ----------------
// BM=64, BN=128, BK=32; 256 threads = 4 waves; wave w owns rows 16w..16w+15.
// MFMA 16x16x32 bf16: A frag A[m=lane&15][k=quad*8+j]; B frag B[k][n=lane&15];
// C/D: col=lane&15, row=quad*4+reg.
#define AS_STRIDE 40
__global__ __launch_bounds__(256) void k_gemm(const float* __restrict__ X,
                                              const unsigned short* __restrict__ WT,
                                              unsigned short* __restrict__ H, int M) {
  __shared__ __align__(16) unsigned short smem[8192];
  unsigned short* As = smem;                   // [64][AS_STRIDE]
  unsigned short* Bs = smem + 64 * AS_STRIDE;  // [128][AS_STRIDE]

  const int tid = threadIdx.x;
  const int wave = tid >> 6;
  const int lane = tid & 63;
  const int m = lane & 15;
  const int quad = lane >> 4;
  const int block_row = blockIdx.x * 64;

  f32x4 acc[8];
#pragma unroll
  for (int t = 0; t < 8; t++) acc[t] = (f32x4){0.f, 0.f, 0.f, 0.f};

  for (int k0 = 0; k0 < 512; k0 += 32) {
#pragma unroll
    for (int it = 0; it < 2; it++) {
      int idx = tid + it * 256;
      int row = idx >> 3;
      int kc = (idx & 7) * 4;
      int gr = block_row + row;
      float4 v = make_float4(0.f, 0.f, 0.f, 0.f);
      if (gr < M) v = *(const float4*)(X + (size_t)gr * 512 + k0 + kc);
      ushort4 b;
      b.x = f2bf(v.x); b.y = f2bf(v.y); b.z = f2bf(v.z); b.w = f2bf(v.w);
      *(ushort4*)&As[row * AS_STRIDE + kc] = b;
    }
#pragma unroll
    for (int it = 0; it < 2; it++) {
      int idx = tid + it * 256;
      int n = idx >> 2;
      int kc = (idx & 3) * 8;
      *(int4*)&Bs[n * AS_STRIDE + kc] = *(const int4*)(WT + (size_t)n * 512 + k0 + kc);
    }
    __syncthreads();

    bf16x8 a = *(bf16x8*)&As[(wave * 16 + m) * AS_STRIDE + quad * 8];
#pragma unroll
    for (int t = 0; t < 8; t++) {
      bf16x8 b = *(bf16x8*)&Bs[(t * 16 + m) * AS_STRIDE + quad * 8];
      acc[t] = __builtin_amdgcn_mfma_f32_16x16x32_bf16(a, b, acc[t], 0, 0, 0);
    }
    __syncthreads();
  }

#pragma unroll
  for (int t = 0; t < 8; t++) {
    int col = t * 16 + m;
#pragma unroll
    for (int r = 0; r < 4; r++) {
      int row = wave * 16 + quad * 4 + r;
      smem[row * 128 + col] = f2bf(acc[t][r]);
    }
  }
  __syncthreads();
#pragma unroll
  for (int it = 0; it < 4; it++) {
    int idx = tid + it * 256;
    int row = idx >> 4;
    int c8 = (idx & 15) * 8;
    int gr = block_row + row;
    if (gr < M)
      *(int4*)(H + (size_t)gr * 128 + c8) = *(int4*)&smem[row * 128 + c8];
  }
}

// ---------------- folded MLP vector ----------------
__global__ __launch_bounds__(128) void k_wsum(const float* __restrict__ mlpW,
                                              const float* __restrict__ mlpb,
                                              float* __restrict__ wsum,
                                              float* __restrict__ bsum) {
  __shared__ float sb[128];
  int k = threadIdx.x;
  float s = 0.f;
  for (int j = 0; j < 128; j++) s += mlpW[k * 128 + j];
  wsum[k] = s;
  sb[k] = mlpb[k];
  __syncthreads();
  for (int off = 64; off > 0; off >>= 1) {
    if (k < off) sb[k] += sb[k + off];
    __syncthreads();
  }
  if (k == 0) bsum[0] = sb[0];
}

// ---------------- aggregation + fused epilogue ----------------
// one wave per dst node; quad g handles edge j0+g (4 edges in flight);
// sub-lane sl owns features 8sl..8sl+7 (one int4 = 8 bf16 = 16B; 16 lanes
// cover the full 256B row). Cross-quad shfl_xor reduce at the end.
__global__ __launch_bounds__(256) void k_agg(const unsigned short* __restrict__ H,
                                             const int* __restrict__ row_start,
                                             const int* __restrict__ deg_d,
                                             const int4* __restrict__ csr,
                                             const float* __restrict__ norm_i,
                                             const float* __restrict__ bias,
                                             const float* __restrict__ alpha,
                                             const float* __restrict__ wsum,
                                             const float* __restrict__ bsum,
                                             float* __restrict__ out, int N) {
  int wave = (blockIdx.x * 256 + threadIdx.x) >> 6;
  int lane = threadIdx.x & 63;
  if (wave >= N) return;
  const int g = lane >> 4;
  const int sl = lane & 15;

  int start = row_start[wave];
  int cnt = deg_d[wave];

  float a1[8], a2[8];
#pragma unroll
  for (int i = 0; i < 8; i++) { a1[i] = 0.f; a2[i] = 0.f; }

  for (int j0 = 0; j0 < cnt; j0 += 4) {
    int j = j0 + g;
    int je = (j < cnt) ? j : cnt - 1;
    int4 ed = csr[start + je];
    float w = (j < cnt) ? __int_as_float(ed.z) : 0.f;
    int4 r1 = *(const int4*)(H + (size_t)ed.x * 128 + sl * 8);
    int4 r2 = *(const int4*)(H + (size_t)ed.y * 128 + sl * 8);
    const unsigned* u1 = (const unsigned*)&r1;
    const unsigned* u2 = (const unsigned*)&r2;
#pragma unroll
    for (int q = 0; q < 4; q++) {
      float2 v1 = bfpair(u1[q]);
      float2 v2 = bfpair(u2[q]);
      a1[2 * q]     = fmaf(v1.x, w, a1[2 * q]);
      a1[2 * q + 1] = fmaf(v1.y, w, a1[2 * q + 1]);
      a2[2 * q]     = fmaf(v2.x, w, a2[2 * q]);
      a2[2 * q + 1] = fmaf(v2.y, w, a2[2 * q + 1]);
    }
  }

  // combine the 4 quads' partial edge-sums (features identical across quads)
#pragma unroll
  for (int i = 0; i < 8; i++) {
    a1[i] += __shfl_xor(a1[i], 16);
    a1[i] += __shfl_xor(a1[i], 32);
    a2[i] += __shfl_xor(a2[i], 16);
    a2[i] += __shfl_xor(a2[i], 32);
  }

  float ni = norm_i[wave];
  float4 bb0 = ((const float4*)bias)[sl * 2];
  float4 bb1 = ((const float4*)bias)[sl * 2 + 1];
  float4 al0 = ((const float4*)alpha)[sl * 2];
  float4 al1 = ((const float4*)alpha)[sl * 2 + 1];
  float4 ws0 = ((const float4*)wsum)[sl * 2];
  float4 ws1 = ((const float4*)wsum)[sl * 2 + 1];
  float bs = bsum[0];
  float bb[8] = {bb0.x, bb0.y, bb0.z, bb0.w, bb1.x, bb1.y, bb1.z, bb1.w};
  float al[8] = {al0.x, al0.y, al0.z, al0.w, al1.x, al1.y, al1.z, al1.w};
  float wsv[8] = {ws0.x, ws0.y, ws0.z, ws0.w, ws1.x, ws1.y, ws1.z, ws1.w};

  float p1 = 0.f, p2 = 0.f;
#pragma unroll
  for (int i = 0; i < 8; i++) {
    float g1 = a1[i] * ni + bb[i];
    float g2 = a2[i] * ni + bb[i];
    g1 = (g1 >= 0.f) ? g1 : al[i] * g1;
    g2 = (g2 >= 0.f) ? g2 : al[i] * g2;
    p1 = fmaf(g1, wsv[i], p1);
    p2 = fmaf(g2, wsv[i], p2);
  }
  // reduce across the 16 sub-lanes (all quads hold identical values)
#pragma unroll
  for (int off = 8; off > 0; off >>= 1) {
    p1 += __shfl_down(p1, off);
    p2 += __shfl_down(p2, off);
  }
  if (lane == 0) {
    out[wave] = p1 + bs;
    out[N + wave] = p2 + bs;
  }
}

// ---------------- launch ----------------

extern "C" void kernel_launch(void* const* d_in, const int* in_sizes, int n_in,
                              void* d_out, int out_size, void* d_ws, size_t ws_size,
                              hipStream_t stream) {
  const float* x = (const float*)d_in[0];
  const int* src = (const int*)d_in[1];
  const int* dst = (const int*)d_in[2];
  const int* perm = (const int*)d_in[3];
  const float* W = (const float*)d_in[4];
  const float* bias = (const float*)d_in[5];
  const float* alpha = (const float*)d_in[6];
  const float* mlpW = (const float*)d_in[7];
  const float* mlpb = (const float*)d_in[8];

  const int E = in_sizes[1];
  const int N = in_sizes[3];
  float* out = (float*)d_out;

  char* ws = (char*)d_ws;
  size_t off = 0;
  auto alloc = [&](size_t bytes) -> void* {
    void* p = ws + off;
    off = (off + bytes + 255) & ~(size_t)255;
    return p;
  };

  unsigned short* h = (unsigned short*)alloc((size_t)N * 128 * sizeof(unsigned short));
  int4* csr = (int4*)alloc((size_t)E * sizeof(int4));
  unsigned short* WT = (unsigned short*)alloc(512 * 128 * sizeof(unsigned short));
  int* deg_s = (int*)alloc((size_t)N * sizeof(int));
  int* deg_d = (int*)alloc((size_t)N * sizeof(int));
  int* cnt = (int*)alloc((size_t)N * sizeof(int));
  int2* pn = (int2*)alloc((size_t)N * sizeof(int2));
  float* norm_i = (float*)alloc((size_t)N * sizeof(float));
  int* row_start = (int*)alloc((size_t)N * sizeof(int));
  float* wsum = (float*)alloc(128 * sizeof(float));
  float* bsum = (float*)alloc(256);
  int* partials = (int*)alloc(512 * sizeof(int));
  int* poff = (int*)alloc(512 * sizeof(int));

  const int nbN = (N + 255) / 256;  // 391 (<=512 for scan_top)
  const int nbE = (E + 255) / 256;

  hipMemsetAsync(deg_s, 0, (size_t)N * sizeof(int), stream);
  hipMemsetAsync(deg_d, 0, (size_t)N * sizeof(int), stream);
  hipMemsetAsync(cnt, 0, (size_t)N * sizeof(int), stream);

  k_degrees<<<nbE, 256, 0, stream>>>(src, dst, deg_s, deg_d, E);
  k_norms<<<nbN, 256, 0, stream>>>(deg_s, deg_d, perm, pn, norm_i, N);
  k_scan_partial<<<nbN, 256, 0, stream>>>(deg_d, partials, N);
  k_scan_top<<<1, 512, 0, stream>>>(partials, poff, nbN);
  k_scan_final<<<nbN, 256, 0, stream>>>(deg_d, poff, row_start, N);
  k_csr_fill<<<nbE, 256, 0, stream>>>(src, dst, pn, row_start, cnt, csr, E);

  k_castw<<<512 * 128 / 256, 256, 0, stream>>>(W, WT);
  k_gemm<<<(N + 63) / 64, 256, 0, stream>>>(x, WT, h, N);
  k_wsum<<<1, 128, 0, stream>>>(mlpW, mlpb, wsum, bsum);

  k_agg<<<(N + 3) / 4, 256, 0, stream>>>(h, row_start, deg_d, csr, norm_i,
                                         bias, alpha, wsum, bsum, out, N);
}